// Round 1
// baseline (100.324 us; speedup 1.0000x reference)
//
#include <hip/hip_runtime.h>
#include <math.h>

// Problem constants (match reference)
#define NB 128
#define NF 2048
#define NE 256

#define WAVES_PER_BLOCK 4
#define FACTS_PER_WAVE 16
#define FACTS_PER_BLOCK (WAVES_PER_BLOCK * FACTS_PER_WAVE)  // 64
#define CHUNKS_PER_B (NF / FACTS_PER_BLOCK)                 // 32

__global__ void init_ws_kernel(unsigned int* ws) {
    int i = blockIdx.x * blockDim.x + threadIdx.x;
    if (i < NB) ws[i] = 0x7F800000u;  // +inf bit pattern
}

__device__ __forceinline__ float sqd4(float4 a, float4 b) {
    float dx = a.x - b.x;
    float dy = a.y - b.y;
    float dz = a.z - b.z;
    float dw = a.w - b.w;
    return dx * dx + dy * dy + dz * dz + dw * dw;
}

__global__ __launch_bounds__(256) void nkb_min_kernel(
    const float* __restrict__ rel,
    const float* __restrict__ arg1,
    const float* __restrict__ arg2,
    const float* __restrict__ fact_rel,
    const float* __restrict__ fact_arg1,
    const float* __restrict__ fact_arg2,
    const int* __restrict__ nb_facts,
    unsigned int* __restrict__ ws)
{
    const int b = blockIdx.x / CHUNKS_PER_B;
    const int chunk = blockIdx.x % CHUNKS_PER_B;
    const int nb = nb_facts[b];
    const int f0 = chunk * FACTS_PER_BLOCK;
    if (f0 >= nb) return;  // block-uniform: skip fully-masked chunks (saves HBM reads)

    const int tid = threadIdx.x;
    const int wave = tid >> 6;
    const int lane = tid & 63;

    // Query fragments: lane l holds floats [4l, 4l+4) of each E=256 vector.
    const float4* qr  = reinterpret_cast<const float4*>(rel  + (size_t)b * NE);
    const float4* qa1 = reinterpret_cast<const float4*>(arg1 + (size_t)b * NE);
    const float4* qa2 = reinterpret_cast<const float4*>(arg2 + (size_t)b * NE);
    const float4 q0 = qr[lane];
    const float4 q1 = qa1[lane];
    const float4 q2 = qa2[lane];

    const float4* fr  = reinterpret_cast<const float4*>(fact_rel  + (size_t)b * NF * NE);
    const float4* fa1 = reinterpret_cast<const float4*>(fact_arg1 + (size_t)b * NF * NE);
    const float4* fa2 = reinterpret_cast<const float4*>(fact_arg2 + (size_t)b * NF * NE);
    // Each fact row = NE/4 = 64 float4 → one wave covers a full row per load.

    float dmin = INFINITY;
    const int fbeg = f0 + wave * FACTS_PER_WAVE;
    const int fend = min(fbeg + FACTS_PER_WAVE, nb);
    for (int f = fbeg; f < fend; ++f) {
        const size_t off = (size_t)f * (NE / 4) + lane;
        float4 v0 = fr[off];
        float4 v1 = fa1[off];
        float4 v2 = fa2[off];
        float d = sqd4(q0, v0) + sqd4(q1, v1) + sqd4(q2, v2);
        // Wave-wide sum (64 lanes)
        #pragma unroll
        for (int s = 1; s < 64; s <<= 1) d += __shfl_xor(d, s);
        dmin = fminf(dmin, d);
    }

    __shared__ float wmin[WAVES_PER_BLOCK];
    if (lane == 0) wmin[wave] = dmin;
    __syncthreads();
    if (tid == 0) {
        float m = wmin[0];
        #pragma unroll
        for (int w = 1; w < WAVES_PER_BLOCK; ++w) m = fminf(m, wmin[w]);
        // d >= 0 always, so uint-bitpattern atomicMin preserves float ordering.
        atomicMin(ws + b, __float_as_uint(m));
    }
}

__global__ void finish_kernel(const unsigned int* __restrict__ ws,
                              const int* __restrict__ nb_facts,
                              float* __restrict__ out) {
    int b = blockIdx.x * blockDim.x + threadIdx.x;
    if (b < NB) {
        float m = __uint_as_float(ws[b]);
        float v = 0.0f;
        if (nb_facts[b] > 0 && isfinite(m)) v = expf(-m);
        out[b] = v;
    }
}

extern "C" void kernel_launch(void* const* d_in, const int* in_sizes, int n_in,
                              void* d_out, int out_size, void* d_ws, size_t ws_size,
                              hipStream_t stream) {
    const float* rel       = (const float*)d_in[0];
    const float* arg1      = (const float*)d_in[1];
    const float* arg2      = (const float*)d_in[2];
    const float* fact_rel  = (const float*)d_in[3];
    const float* fact_arg1 = (const float*)d_in[4];
    const float* fact_arg2 = (const float*)d_in[5];
    const int*   nb_facts  = (const int*)d_in[6];
    float* out = (float*)d_out;
    unsigned int* ws = (unsigned int*)d_ws;

    // 1) init per-batch min slots to +inf (harness does not re-poison ws between replays)
    init_ws_kernel<<<1, NB, 0, stream>>>(ws);

    // 2) masked min of squared distances
    const int grid = NB * CHUNKS_PER_B;  // 4096 blocks
    nkb_min_kernel<<<grid, 256, 0, stream>>>(rel, arg1, arg2,
                                             fact_rel, fact_arg1, fact_arg2,
                                             nb_facts, ws);

    // 3) out[b] = nb>0 ? exp(-min) : 0
    finish_kernel<<<1, NB, 0, stream>>>(ws, nb_facts, out);
}

// Round 2
// 91.797 us; speedup vs baseline: 1.0929x; 1.0929x over previous
//
#include <hip/hip_runtime.h>
#include <math.h>

// Problem constants (match reference)
#define NB 128
#define NF 2048
#define NE 256
#define NF4 (NE / 4)  // 64 float4 per fact row per tensor

#define WAVES_PER_BLOCK 4
#define FACTS_PER_WAVE 16
#define FACTS_PER_BLOCK (WAVES_PER_BLOCK * FACTS_PER_WAVE)  // 64
#define CHUNKS_PER_B (NF / FACTS_PER_BLOCK)                 // 32

__global__ void init_ws_kernel(unsigned int* ws) {
    int i = blockIdx.x * blockDim.x + threadIdx.x;
    if (i < NB) ws[i] = 0x7F800000u;  // +inf bit pattern
}

__device__ __forceinline__ float sqd4(float4 a, float4 b) {
    float dx = a.x - b.x;
    float dy = a.y - b.y;
    float dz = a.z - b.z;
    float dw = a.w - b.w;
    return dx * dx + dy * dy + dz * dz + dw * dw;
}

// Layout: 16 lanes per fact, 4 facts per wave-pass.
//   sub = lane>>4 : which fact of the quad this lane works on
//   seg = lane&15 : which float4 segment (of 16 per quarter-row) this lane reads
// Each lane covers floats [4*(seg+16*it)] for it=0..3 of each E=256 vector.
// Per pass: 12 independent float4 loads in flight (4 facts x 3 tensors),
// then 4 shuffles reduce ALL four facts simultaneously (disjoint 16-lane groups).
__global__ __launch_bounds__(256) void nkb_min_kernel(
    const float* __restrict__ rel,
    const float* __restrict__ arg1,
    const float* __restrict__ arg2,
    const float* __restrict__ fact_rel,
    const float* __restrict__ fact_arg1,
    const float* __restrict__ fact_arg2,
    const int* __restrict__ nb_facts,
    unsigned int* __restrict__ ws)
{
    const int b = blockIdx.x / CHUNKS_PER_B;
    const int chunk = blockIdx.x % CHUNKS_PER_B;
    const int nb = nb_facts[b];
    const int f0 = chunk * FACTS_PER_BLOCK;
    if (f0 >= nb) return;  // block-uniform early exit: masked facts are never read

    const int tid = threadIdx.x;
    const int wave = tid >> 6;
    const int lane = tid & 63;
    const int sub = lane >> 4;
    const int seg = lane & 15;

    const int fbeg = f0 + wave * FACTS_PER_WAVE;
    if (fbeg >= nb) return;  // wave-uniform exit; no barriers in this kernel, so safe
    const int fend = min(fbeg + FACTS_PER_WAVE, nb);

    // Query fragments (reused across all facts): 12 float4 = 48 VGPRs
    const float4* qr  = reinterpret_cast<const float4*>(rel  + (size_t)b * NE);
    const float4* qa1 = reinterpret_cast<const float4*>(arg1 + (size_t)b * NE);
    const float4* qa2 = reinterpret_cast<const float4*>(arg2 + (size_t)b * NE);
    float4 q0[4], q1[4], q2[4];
    #pragma unroll
    for (int it = 0; it < 4; ++it) {
        q0[it] = qr[seg + 16 * it];
        q1[it] = qa1[seg + 16 * it];
        q2[it] = qa2[seg + 16 * it];
    }

    const float4* fr  = reinterpret_cast<const float4*>(fact_rel  + (size_t)b * NF * NE);
    const float4* fa1 = reinterpret_cast<const float4*>(fact_arg1 + (size_t)b * NF * NE);
    const float4* fa2 = reinterpret_cast<const float4*>(fact_arg2 + (size_t)b * NF * NE);

    float dmin = INFINITY;
    for (int fq = fbeg; fq < fend; fq += 4) {
        const int f = fq + sub;  // may exceed nb in a partial quad (masked below);
                                 // always < NF since fq is 4-aligned and < nb <= 2048
        const size_t base = (size_t)f * NF4;

        // Issue all 12 loads before consuming — the MLP source.
        float4 v0[4], v1[4], v2[4];
        #pragma unroll
        for (int it = 0; it < 4; ++it) v0[it] = fr[base + seg + 16 * it];
        #pragma unroll
        for (int it = 0; it < 4; ++it) v1[it] = fa1[base + seg + 16 * it];
        #pragma unroll
        for (int it = 0; it < 4; ++it) v2[it] = fa2[base + seg + 16 * it];

        float acc = 0.0f;
        #pragma unroll
        for (int it = 0; it < 4; ++it)
            acc += sqd4(q0[it], v0[it]) + sqd4(q1[it], v1[it]) + sqd4(q2[it], v2[it]);

        // Sum across each 16-lane group: 4 shuffles reduce 4 facts at once.
        #pragma unroll
        for (int s = 1; s < 16; s <<= 1) acc += __shfl_xor(acc, s);

        if (f < nb) dmin = fminf(dmin, acc);
    }

    // Combine the 4 groups' running minima (group lanes hold identical values).
    dmin = fminf(dmin, __shfl_xor(dmin, 16));
    dmin = fminf(dmin, __shfl_xor(dmin, 32));

    if (lane == 0) atomicMin(ws + b, __float_as_uint(dmin));  // d >= 0: uint order == float order
}

__global__ void finish_kernel(const unsigned int* __restrict__ ws,
                              const int* __restrict__ nb_facts,
                              float* __restrict__ out) {
    int b = blockIdx.x * blockDim.x + threadIdx.x;
    if (b < NB) {
        float m = __uint_as_float(ws[b]);
        float v = 0.0f;
        if (nb_facts[b] > 0 && isfinite(m)) v = expf(-m);
        out[b] = v;
    }
}

extern "C" void kernel_launch(void* const* d_in, const int* in_sizes, int n_in,
                              void* d_out, int out_size, void* d_ws, size_t ws_size,
                              hipStream_t stream) {
    const float* rel       = (const float*)d_in[0];
    const float* arg1      = (const float*)d_in[1];
    const float* arg2      = (const float*)d_in[2];
    const float* fact_rel  = (const float*)d_in[3];
    const float* fact_arg1 = (const float*)d_in[4];
    const float* fact_arg2 = (const float*)d_in[5];
    const int*   nb_facts  = (const int*)d_in[6];
    float* out = (float*)d_out;
    unsigned int* ws = (unsigned int*)d_ws;

    // 1) init per-batch min slots to +inf (harness does not re-poison ws between replays)
    init_ws_kernel<<<1, NB, 0, stream>>>(ws);

    // 2) masked min of squared distances
    const int grid = NB * CHUNKS_PER_B;  // 4096 blocks
    nkb_min_kernel<<<grid, 256, 0, stream>>>(rel, arg1, arg2,
                                             fact_rel, fact_arg1, fact_arg2,
                                             nb_facts, ws);

    // 3) out[b] = nb>0 ? exp(-min) : 0
    finish_kernel<<<1, NB, 0, stream>>>(ws, nb_facts, out);
}

// Round 3
// 80.770 us; speedup vs baseline: 1.2421x; 1.1365x over previous
//
#include <hip/hip_runtime.h>
#include <math.h>

// Problem constants (match reference)
#define NB 128
#define NF 2048
#define NE 256
#define NF4 (NE / 4)  // 64 float4 per fact row per tensor

#define WAVES_PER_BLOCK 4
#define FACTS_PER_WAVE 16
#define FACTS_PER_BLOCK (WAVES_PER_BLOCK * FACTS_PER_WAVE)  // 64
#define CHUNKS_PER_B (NF / FACTS_PER_BLOCK)                 // 32
#define NPASS (FACTS_PER_WAVE / 2)                          // 8 passes, 2 facts each

__device__ __forceinline__ float sqd4(float4 a, float4 b) {
    float dx = a.x - b.x;
    float dy = a.y - b.y;
    float dz = a.z - b.z;
    float dw = a.w - b.w;
    return dx * dx + dy * dy + dz * dz + dw * dw;
}

// Layout: 32 lanes per fact (seg = lane&31 covers float4 seg and seg+32),
// 2 facts per pass (sub = lane>>5), 8 passes = 16 facts per wave.
// Fact indices are CLAMPED to nb-1 so every pass is a full, compile-time
// pass (duplicate reads of row nb-1 are masked out of the min by the f<nb
// predicate). This makes the 8-pass loop fully unrollable, and we explicitly
// double-buffer: pass k+1's 6 loads are issued before pass k's compute, so
// HBM latency hides under VALU + shuffle work of the previous pass.
__global__ __launch_bounds__(256, 4) void nkb_min_kernel(
    const float* __restrict__ rel,
    const float* __restrict__ arg1,
    const float* __restrict__ arg2,
    const float* __restrict__ fact_rel,
    const float* __restrict__ fact_arg1,
    const float* __restrict__ fact_arg2,
    const int* __restrict__ nb_facts,
    float* __restrict__ ws)
{
    const int b = blockIdx.x >> 5;        // / CHUNKS_PER_B
    const int chunk = blockIdx.x & 31;    // % CHUNKS_PER_B
    const int nb = nb_facts[b];
    const int tid = threadIdx.x;
    const int wave = tid >> 6;
    const int lane = tid & 63;
    const int sub = lane >> 5;   // which of the 2 facts in a pass
    const int seg = lane & 31;   // float4 segment (covers seg and seg+32)

    const int fbeg = chunk * FACTS_PER_BLOCK + wave * FACTS_PER_WAVE;
    float dmin = INFINITY;

    if (fbeg < nb) {  // wave-uniform; dead waves fall through to block reduce
        // Query fragments: 6 float4 = 24 VGPRs, reused across all facts.
        const float4* qr  = reinterpret_cast<const float4*>(rel  + (size_t)b * NE);
        const float4* qa1 = reinterpret_cast<const float4*>(arg1 + (size_t)b * NE);
        const float4* qa2 = reinterpret_cast<const float4*>(arg2 + (size_t)b * NE);
        float4 q0[2], q1[2], q2[2];
        #pragma unroll
        for (int it = 0; it < 2; ++it) {
            q0[it] = qr [seg + 32 * it];
            q1[it] = qa1[seg + 32 * it];
            q2[it] = qa2[seg + 32 * it];
        }

        const float4* fr  = reinterpret_cast<const float4*>(fact_rel  + (size_t)b * NF * NE);
        const float4* fa1 = reinterpret_cast<const float4*>(fact_arg1 + (size_t)b * NF * NE);
        const float4* fa2 = reinterpret_cast<const float4*>(fact_arg2 + (size_t)b * NF * NE);

        const int fmax = nb - 1;  // nb >= 1 here
        float4 A0[2], A1[2], A2[2], B0[2], B1[2], B2[2];

        // Prologue: load pass 0
        {
            const int f = min(fbeg + sub, fmax);
            const size_t base = (size_t)f * NF4 + seg;
            #pragma unroll
            for (int it = 0; it < 2; ++it) {
                A0[it] = fr [base + 32 * it];
                A1[it] = fa1[base + 32 * it];
                A2[it] = fa2[base + 32 * it];
            }
        }

        #pragma unroll
        for (int k = 0; k < NPASS; ++k) {
            // Issue next pass's loads BEFORE computing this pass.
            if (k + 1 < NPASS) {
                const int f = min(fbeg + 2 * (k + 1) + sub, fmax);
                const size_t base = (size_t)f * NF4 + seg;
                #pragma unroll
                for (int it = 0; it < 2; ++it) {
                    B0[it] = fr [base + 32 * it];
                    B1[it] = fa1[base + 32 * it];
                    B2[it] = fa2[base + 32 * it];
                }
            }
            float acc = 0.0f;
            #pragma unroll
            for (int it = 0; it < 2; ++it)
                acc += sqd4(q0[it], A0[it]) + sqd4(q1[it], A1[it]) + sqd4(q2[it], A2[it]);
            // Sum within each 32-lane group (both facts reduced simultaneously).
            #pragma unroll
            for (int s = 1; s < 32; s <<= 1) acc += __shfl_xor(acc, s);
            if (fbeg + 2 * k + sub < nb) dmin = fminf(dmin, acc);
            if (k + 1 < NPASS) {
                #pragma unroll
                for (int it = 0; it < 2; ++it) {
                    A0[it] = B0[it]; A1[it] = B1[it]; A2[it] = B2[it];
                }
            }
        }
        // Combine the two 32-lane groups' minima.
        dmin = fminf(dmin, __shfl_xor(dmin, 32));
    }

    __shared__ float wmin[WAVES_PER_BLOCK];
    if (lane == 0) wmin[wave] = dmin;
    __syncthreads();
    if (tid == 0) {
        float m = fminf(fminf(wmin[0], wmin[1]), fminf(wmin[2], wmin[3]));
        // ws layout [chunk][b] so finish_kernel reads coalesced.
        // Every block (live or dead) writes exactly once -> no init kernel,
        // no atomics, deterministic across graph replays.
        ws[chunk * NB + b] = m;
    }
}

__global__ void finish_kernel(const float* __restrict__ ws,
                              const int* __restrict__ nb_facts,
                              float* __restrict__ out) {
    const int b = threadIdx.x;  // 128 threads, 1 block
    float m = INFINITY;
    #pragma unroll
    for (int c = 0; c < CHUNKS_PER_B; ++c)
        m = fminf(m, ws[c * NB + b]);
    float v = 0.0f;
    if (nb_facts[b] > 0 && isfinite(m)) v = expf(-m);
    out[b] = v;
}

extern "C" void kernel_launch(void* const* d_in, const int* in_sizes, int n_in,
                              void* d_out, int out_size, void* d_ws, size_t ws_size,
                              hipStream_t stream) {
    const float* rel       = (const float*)d_in[0];
    const float* arg1      = (const float*)d_in[1];
    const float* arg2      = (const float*)d_in[2];
    const float* fact_rel  = (const float*)d_in[3];
    const float* fact_arg1 = (const float*)d_in[4];
    const float* fact_arg2 = (const float*)d_in[5];
    const int*   nb_facts  = (const int*)d_in[6];
    float* out = (float*)d_out;
    float* ws  = (float*)d_ws;

    // 1) masked, pipelined min of squared distances; each block writes its
    //    chunk-min (dead blocks write +inf) -> ws fully rewritten every call.
    const int grid = NB * CHUNKS_PER_B;  // 4096 blocks
    nkb_min_kernel<<<grid, 256, 0, stream>>>(rel, arg1, arg2,
                                             fact_rel, fact_arg1, fact_arg2,
                                             nb_facts, ws);

    // 2) out[b] = nb>0 ? exp(-min) : 0
    finish_kernel<<<1, NB, 0, stream>>>(ws, nb_facts, out);
}